// Round 11
// baseline (1979.903 us; speedup 1.0000x reference)
//
#include <hip/hip_runtime.h>

typedef unsigned short u16;
typedef unsigned int u32;
typedef __bf16 bf16;
typedef __attribute__((ext_vector_type(8))) bf16 bf16x8;
typedef __attribute__((ext_vector_type(4))) float f32x4;
typedef __attribute__((ext_vector_type(8))) u16 u16x8;
typedef __attribute__((ext_vector_type(4))) u16 u16x4;

#define M_DIM 8192
#define N_DIM 4096
#define K_DIM 4096
#define NTK   (K_DIM / 32)   // 128 K-tiles of 32

__device__ __forceinline__ u16 f2bf(float f) {
    u32 u = __float_as_uint(f);
    u32 r = (u + 0x7fffu + ((u >> 16) & 1u)) >> 16;
    return (u16)r;
}

__device__ __forceinline__ float softplus_f(float x) {
    return fmaxf(x, 0.f) + log1pf(expf(-fabsf(x)));
}

__device__ __forceinline__ void gload_lds16(const void* g, void* l) {
    __builtin_amdgcn_global_load_lds(
        (const __attribute__((address_space(1))) void*)g,
        (__attribute__((address_space(3))) void*)l,
        16, 0, 0);
}

// ---------------- x -> bf16 cast ----------------
__global__ void conv_x_kernel(const float* __restrict__ x, u16* __restrict__ xb,
                              long long n8) {
    long long idx = blockIdx.x * (long long)blockDim.x + threadIdx.x;
    long long stride = gridDim.x * (long long)blockDim.x;
    for (long long i = idx; i < n8; i += stride) {
        const float4* xp = (const float4*)(x + i * 8);
        float4 a = xp[0], b = xp[1];
        u16x8 r;
        r[0] = f2bf(a.x); r[1] = f2bf(a.y); r[2] = f2bf(a.z); r[3] = f2bf(a.w);
        r[4] = f2bf(b.x); r[5] = f2bf(b.y); r[6] = f2bf(b.z); r[7] = f2bf(b.w);
        *(u16x8*)(xb + i * 8) = r;
    }
}

// ------- W sample + transpose (vectorized): Wt[n][k] = bf16(w_loc + sp(w_std)*eps_w) -------
__global__ void wconv_kernel(const float* __restrict__ w_loc,
                             const float* __restrict__ w_std,
                             const float* __restrict__ eps_w,
                             u16* __restrict__ wt) {
    __shared__ u16 t[64][67];
    const int kb = blockIdx.x & 63;
    const int nb = blockIdx.x >> 6;
    const int k0 = kb * 64, n0 = nb * 64;
    const int tr = threadIdx.x >> 4;        // 0..15
    const int tc = (threadIdx.x & 15) * 4;  // 0..60
#pragma unroll
    for (int s = 0; s < 4; ++s) {
        const int kr = s * 16 + tr;
        const size_t off = (size_t)(k0 + kr) * N_DIM + n0 + tc;
        float4 wl = *(const float4*)(w_loc + off);
        float4 ws = *(const float4*)(w_std + off);
        float4 ew = *(const float4*)(eps_w + off);
        t[kr][tc + 0] = f2bf(wl.x + softplus_f(ws.x) * ew.x);
        t[kr][tc + 1] = f2bf(wl.y + softplus_f(ws.y) * ew.y);
        t[kr][tc + 2] = f2bf(wl.z + softplus_f(ws.z) * ew.z);
        t[kr][tc + 3] = f2bf(wl.w + softplus_f(ws.w) * ew.w);
    }
    __syncthreads();
#pragma unroll
    for (int s = 0; s < 4; ++s) {
        const int nr = s * 16 + tr;
        u16x4 v;
        v[0] = t[tc + 0][nr];
        v[1] = t[tc + 1][nr];
        v[2] = t[tc + 2][nr];
        v[3] = t[tc + 3][nr];
        *(u16x4*)&wt[(size_t)(n0 + nr) * K_DIM + k0 + tc] = v;
    }
}

// ---------------- bias ----------------
__global__ void bias_kernel(const float* __restrict__ b_loc,
                            const float* __restrict__ b_std,
                            const float* __restrict__ eps_b,
                            float* __restrict__ bias) {
    int i = blockIdx.x * blockDim.x + threadIdx.x;
    if (i < N_DIM) bias[i] = b_loc[i] + softplus_f(b_std[i]) * eps_b[i];
}

// ------- 256x256 bf16 GEMM, BK=32, 80 KiB LDS -> 2 BLOCKS/CU co-resident -------
// C[M][N] = Xb[M][K] @ Wt[N][K]^T + bias. 8 waves (2Mx4N) per block.
// Round-11 lever (occupancy): LDS = A[2][256][32] (32K) + B[3][256][32] (48K)
// = 80 KiB exactly -> 2 blocks/CU (160 KiB total), 4 waves/SIMD, all 512
// blocks co-resident. Co-resident blocks are NOT barrier-synchronized, so one
// block's LDS-read burst overlaps the other block's MFMA backlog (m114/m97
// mechanism) -- the overlap that intra-block reordering (r7-r10, all ~53%)
// could not create. __launch_bounds__(512,4) caps VGPR at 128 for 4 waves/SIMD.
// Schedule per tile u (r10's, halved): {b(4)+aA(4) ds_reads, stageA(u+1)(2),
// 16 MFMA, aB(4) reads, stageB(u+2)(2), 16 MFMA, vmcnt(2), sched_barrier,
// s_barrier}. Slot safety as r7 (counts halved): stageA parity-disjoint from
// A(u); B slots u,u+1,u+2 distinct mod 3; end-of-tile vmcnt(2) leaves exactly
// B(u+2) in flight (A(u+1),B(u+1) resident) -- never drains mid-loop.
// Swizzle (64B rows, = round-3's measured-0-conflict pattern): read granule
// hi ^ ((fr>>1)&3); bank-quad 4*(fr&1) + granule covers all 8 quads per
// 8-lane group. DMA source pre-swizzled q = (tid&3)^((tid>>3)&3), linear dest.
__global__ __launch_bounds__(512, 4) void gemm_kernel(
    const u16* __restrict__ Xb, const u16* __restrict__ Wt,
    const float* __restrict__ bias, float* __restrict__ C) {
    extern __shared__ __align__(16) u16 lds[];   // 40960 elems = 80 KiB

    const int tid = threadIdx.x;
    const int l  = tid & 63;
    const int w  = tid >> 6;          // wave 0..7
    const int wm = w >> 2;            // 0..1
    const int wn = w & 3;             // 0..3

    // T1: XCD-bijective swizzle (512 blocks, 512 % 8 == 0)
    const int swz = (blockIdx.x & 7) * 64 + (blockIdx.x >> 3);
    const int m0 = (swz >> 4) * 256;  // 32 M-tiles
    const int n0 = (swz & 15) * 256;  // 16 N-tiles

    const u16* Ab = Xb + (size_t)m0 * K_DIM;
    const u16* Bb = Wt + (size_t)n0 * K_DIM;

    // staging: row = s*128 + tid>>2, LDS granule tid&3 (linear dest),
    // source granule pre-swizzled: (tid&3) ^ ((row>>1)&3) = (tid&3)^((tid>>3)&3)
    const int sq = ((tid & 3) ^ ((tid >> 3) & 3)) * 8;   // col elems

    // reads: fr = row-within-16, hi = k-granule (0..3)
    const int fr = l & 15, hi = l >> 4;
    const int ce = (hi ^ ((fr >> 1) & 3)) << 3;          // col elems

    auto stageA = [&](int u) {
#pragma unroll
        for (int s = 0; s < 2; ++s) {
            const u16* g = Ab + (size_t)(s * 128 + (tid >> 2)) * K_DIM + u * 32 + sq;
            gload_lds16(g, &lds[(u & 1) * 8192 + s * 4096 + tid * 8]);
        }
    };
    auto stageB = [&](int u, int slot) {
#pragma unroll
        for (int s = 0; s < 2; ++s) {
            const u16* g = Bb + (size_t)(s * 128 + (tid >> 2)) * K_DIM + u * 32 + sq;
            gload_lds16(g, &lds[16384 + slot * 8192 + s * 4096 + tid * 8]);
        }
    };

    f32x4 acc[8][4] = {};

    // ---- prologue: A(0), B(0)->slot0, B(1)->slot1; wait A(0),B(0) ----
    stageA(0);
    stageB(0, 0);
    stageB(1, 1);
    asm volatile("s_waitcnt vmcnt(2)" ::: "memory");
    __builtin_amdgcn_sched_barrier(0);
    __builtin_amdgcn_s_barrier();

#define MFMA16(O, AV, BV)                                                     \
    _Pragma("unroll") for (int mb = 0; mb < 4; ++mb)                          \
    _Pragma("unroll") for (int nb = 0; nb < 4; ++nb)                          \
        acc[(O) + mb][nb] = __builtin_amdgcn_mfma_f32_16x16x32_bf16(          \
            AV[mb], BV[nb], acc[(O) + mb][nb], 0, 0, 0);

    int scur = 0, snxt = 2;   // B slot of tile u; slot for B(u+2)
    for (int u = 0; u < NTK; ++u) {
        const int ab = (u & 1) * 8192 + (wm * 128 + fr) * 32;
        const int bb = 16384 + scur * 8192 + (wn * 64 + fr) * 32;
        bf16x8 b[4], aA[4], aB[4];

        // ---- cluster 0: b(4) + a m0-3 (4) reads; stage A(u+1); 16 MFMA ----
#pragma unroll
        for (int nb = 0; nb < 4; ++nb)
            b[nb] = *(const bf16x8*)&lds[bb + nb * 512 + ce];
#pragma unroll
        for (int mb = 0; mb < 4; ++mb)
            aA[mb] = *(const bf16x8*)&lds[ab + mb * 512 + ce];
        if (u + 1 < NTK) stageA(u + 1);
        __builtin_amdgcn_s_setprio(1);
        MFMA16(0, aA, b);
        __builtin_amdgcn_s_setprio(0);

        // ---- cluster 1: a m4-7 (4) reads; stage B(u+2); 16 MFMA ----
#pragma unroll
        for (int mb = 0; mb < 4; ++mb)
            aB[mb] = *(const bf16x8*)&lds[ab + (mb + 4) * 512 + ce];
        if (u + 2 < NTK) stageB(u + 2, snxt);
        __builtin_amdgcn_s_setprio(1);
        MFMA16(4, aB, b);
        __builtin_amdgcn_s_setprio(0);

        // counted drain: leave exactly B(u+2) (newest 2 DMAs) in flight
        if (u + 2 < NTK) {
            asm volatile("s_waitcnt vmcnt(2)" ::: "memory");
        } else if (u + 1 < NTK) {
            asm volatile("s_waitcnt vmcnt(0)" ::: "memory");
        }
        __builtin_amdgcn_sched_barrier(0);
        __builtin_amdgcn_s_barrier();

        scur = (scur == 2) ? 0 : scur + 1;
        snxt = (snxt == 2) ? 0 : snxt + 1;
    }
#undef MFMA16

    // ---- epilogue: C/D layout col=lane&15, row=(lane>>4)*4+reg ----
    const int orow0 = m0 + wm * 128;
    const int ocol0 = n0 + wn * 64;
    float bv[4];
#pragma unroll
    for (int nb = 0; nb < 4; ++nb) bv[nb] = bias[ocol0 + nb * 16 + fr];
#pragma unroll
    for (int mb = 0; mb < 8; ++mb)
#pragma unroll
        for (int nb = 0; nb < 4; ++nb)
#pragma unroll
            for (int j = 0; j < 4; ++j)
                C[(size_t)(orow0 + mb * 16 + hi * 4 + j) * N_DIM
                  + ocol0 + nb * 16 + fr] = acc[mb][nb][j] + bv[nb];
}

extern "C" void kernel_launch(void* const* d_in, const int* in_sizes, int n_in,
                              void* d_out, int out_size, void* d_ws, size_t ws_size,
                              hipStream_t stream) {
    const float* x     = (const float*)d_in[0];
    const float* w_loc = (const float*)d_in[1];
    const float* w_std = (const float*)d_in[2];
    const float* b_loc = (const float*)d_in[3];
    const float* b_std = (const float*)d_in[4];
    const float* eps_w = (const float*)d_in[5];
    const float* eps_b = (const float*)d_in[6];
    float* out = (float*)d_out;

    char* ws = (char*)d_ws;
    u16* Xb   = (u16*)ws;                                            // 64 MB
    u16* Wt   = (u16*)(ws + (size_t)M_DIM * K_DIM * 2);              // 32 MB
    float* bv = (float*)(ws + (size_t)M_DIM * K_DIM * 2
                            + (size_t)N_DIM * K_DIM * 2);            // 16 KB

    (void)hipFuncSetAttribute((const void*)gemm_kernel,
                              hipFuncAttributeMaxDynamicSharedMemorySize, 81920);

    conv_x_kernel<<<2048, 256, 0, stream>>>(x, Xb, (long long)M_DIM * K_DIM / 8);
    wconv_kernel<<<(K_DIM / 64) * (N_DIM / 64), 256, 0, stream>>>(w_loc, w_std, eps_w, Wt);
    bias_kernel<<<N_DIM / 256, 256, 0, stream>>>(b_loc, b_std, eps_b, bv);
    gemm_kernel<<<(M_DIM / 256) * (N_DIM / 256), 512, 81920, stream>>>(Xb, Wt, bv, out);
}

// Round 12
// 414.938 us; speedup vs baseline: 4.7716x; 4.7716x over previous
//
#include <hip/hip_runtime.h>

typedef unsigned short u16;
typedef unsigned int u32;
typedef __bf16 bf16;
typedef __attribute__((ext_vector_type(8))) bf16 bf16x8;
typedef __attribute__((ext_vector_type(4))) float f32x4;
typedef __attribute__((ext_vector_type(8))) u16 u16x8;
typedef __attribute__((ext_vector_type(4))) u16 u16x4;

#define M_DIM 8192
#define N_DIM 4096
#define K_DIM 4096
#define NTK   (K_DIM / 32)   // 128 K-tiles of 32

__device__ __forceinline__ u16 f2bf(float f) {
    u32 u = __float_as_uint(f);
    u32 r = (u + 0x7fffu + ((u >> 16) & 1u)) >> 16;
    return (u16)r;
}

__device__ __forceinline__ float softplus_f(float x) {
    return fmaxf(x, 0.f) + log1pf(expf(-fabsf(x)));
}

__device__ __forceinline__ void gload_lds16(const void* g, void* l) {
    __builtin_amdgcn_global_load_lds(
        (const __attribute__((address_space(1))) void*)g,
        (__attribute__((address_space(3))) void*)l,
        16, 0, 0);
}

// ---------------- x -> bf16 cast ----------------
__global__ void conv_x_kernel(const float* __restrict__ x, u16* __restrict__ xb,
                              long long n8) {
    long long idx = blockIdx.x * (long long)blockDim.x + threadIdx.x;
    long long stride = gridDim.x * (long long)blockDim.x;
    for (long long i = idx; i < n8; i += stride) {
        const float4* xp = (const float4*)(x + i * 8);
        float4 a = xp[0], b = xp[1];
        u16x8 r;
        r[0] = f2bf(a.x); r[1] = f2bf(a.y); r[2] = f2bf(a.z); r[3] = f2bf(a.w);
        r[4] = f2bf(b.x); r[5] = f2bf(b.y); r[6] = f2bf(b.z); r[7] = f2bf(b.w);
        *(u16x8*)(xb + i * 8) = r;
    }
}

// ------- W sample + transpose (vectorized): Wt[n][k] = bf16(w_loc + sp(w_std)*eps_w) -------
__global__ void wconv_kernel(const float* __restrict__ w_loc,
                             const float* __restrict__ w_std,
                             const float* __restrict__ eps_w,
                             u16* __restrict__ wt) {
    __shared__ u16 t[64][67];
    const int kb = blockIdx.x & 63;
    const int nb = blockIdx.x >> 6;
    const int k0 = kb * 64, n0 = nb * 64;
    const int tr = threadIdx.x >> 4;        // 0..15
    const int tc = (threadIdx.x & 15) * 4;  // 0..60
#pragma unroll
    for (int s = 0; s < 4; ++s) {
        const int kr = s * 16 + tr;
        const size_t off = (size_t)(k0 + kr) * N_DIM + n0 + tc;
        float4 wl = *(const float4*)(w_loc + off);
        float4 ws = *(const float4*)(w_std + off);
        float4 ew = *(const float4*)(eps_w + off);
        t[kr][tc + 0] = f2bf(wl.x + softplus_f(ws.x) * ew.x);
        t[kr][tc + 1] = f2bf(wl.y + softplus_f(ws.y) * ew.y);
        t[kr][tc + 2] = f2bf(wl.z + softplus_f(ws.z) * ew.z);
        t[kr][tc + 3] = f2bf(wl.w + softplus_f(ws.w) * ew.w);
    }
    __syncthreads();
#pragma unroll
    for (int s = 0; s < 4; ++s) {
        const int nr = s * 16 + tr;
        u16x4 v;
        v[0] = t[tc + 0][nr];
        v[1] = t[tc + 1][nr];
        v[2] = t[tc + 2][nr];
        v[3] = t[tc + 3][nr];
        *(u16x4*)&wt[(size_t)(n0 + nr) * K_DIM + k0 + tc] = v;
    }
}

// ------- 256x256 bf16 GEMM, 16 waves (4Mx4N), 4 waves/SIMD, BK=32 -------
// C[M][N] = Xb[M][K] @ Wt[N][K]^T + bias(fused). 80 KiB LDS:
// A double-buffered [2][256][32] @0, B TRIPLE-buffered [3][256][32] @16384.
// Round-12 lever (r11 root cause fixed): 4 waves/SIMD needs <=128 VGPR/wave
// (pool = 512/SIMD). Per-wave output 64x64 -> acc[4][4]=64 + frags 32 +
// addressing ~15 = ~110 <= 128, no spill. 16 waves give the SIMD 4
// independent instruction streams so ds_read/lgkm stalls of one wave hide
// under another's MFMA backlog -- the overlap 2-wave lockstep (r7-r10, all
// ~54% MfmaUtil) could not create. 1024 threads stage a full 16 KB operand
// tile with ONE gload_lds per thread.
// Per tile u: {b(4)+a(4) ds_reads | stageA(u+1) + stageB(u+2) | 16 MFMA |
// vmcnt(1) | sched_barrier | s_barrier}. Steady state: only B(u+2) in
// flight after the wait; never drains to 0 mid-loop. Slot safety as r7:
// A parity-disjoint, B slots u,u+1,u+2 distinct mod 3; all reads of a
// buffer are consumed by MFMAs before the tile's closing barrier.
// Swizzle (64B rows, r3/r11 measured-0-conflict): read granule
// hi ^ ((fr>>1)&3) -> bank-quads 4*(fr&1)+g cover all 8 per 8-lane group;
// DMA source pre-swizzled q = (tid&3)^((tid>>3)&3), linear dest (rule #21).
__global__ __launch_bounds__(1024, 4) void gemm_kernel(
    const u16* __restrict__ Xb, const u16* __restrict__ Wt,
    const float* __restrict__ b_loc, const float* __restrict__ b_std,
    const float* __restrict__ eps_b, float* __restrict__ C) {
    extern __shared__ __align__(16) u16 lds[];   // 40960 elems = 80 KiB

    const int tid = threadIdx.x;
    const int l  = tid & 63;
    const int w  = tid >> 6;          // wave 0..15
    const int wm = w >> 2;            // 0..3 (64-row band)
    const int wn = w & 3;             // 0..3 (64-col band)

    // T1: XCD-bijective swizzle (512 blocks, 512 % 8 == 0)
    const int swz = (blockIdx.x & 7) * 64 + (blockIdx.x >> 3);
    const int m0 = (swz >> 4) * 256;  // 32 M-tiles
    const int n0 = (swz & 15) * 256;  // 16 N-tiles

    const u16* Ab = Xb + (size_t)m0 * K_DIM;
    const u16* Bb = Wt + (size_t)n0 * K_DIM;

    // staging: row = tid>>2 (0..255), LDS granule tid&3 (linear dest),
    // source granule pre-swizzled: (tid&3) ^ ((row>>1)&3) = (tid&3)^((tid>>3)&3)
    const int sq = ((tid & 3) ^ ((tid >> 3) & 3)) * 8;   // col elems

    // reads: fr = row-within-16, hi = k-granule (0..3)
    const int fr = l & 15, hi = l >> 4;
    const int ce = (hi ^ ((fr >> 1) & 3)) << 3;          // col elems

    auto stageA = [&](int u) {
        const u16* g = Ab + (size_t)(tid >> 2) * K_DIM + u * 32 + sq;
        gload_lds16(g, &lds[(u & 1) * 8192 + tid * 8]);
    };
    auto stageB = [&](int u, int slot) {
        const u16* g = Bb + (size_t)(tid >> 2) * K_DIM + u * 32 + sq;
        gload_lds16(g, &lds[16384 + slot * 8192 + tid * 8]);
    };

    f32x4 acc[4][4] = {};

    // ---- prologue: A(0), B(0)->slot0, B(1)->slot1; wait A(0),B(0) ----
    stageA(0);
    stageB(0, 0);
    stageB(1, 1);
    asm volatile("s_waitcnt vmcnt(1)" ::: "memory");
    __builtin_amdgcn_sched_barrier(0);
    __builtin_amdgcn_s_barrier();

    int scur = 0, snxt = 2;   // B slot of tile u; slot for B(u+2)
    for (int u = 0; u < NTK; ++u) {
        const int ab = (u & 1) * 8192 + (wm * 64 + fr) * 32;
        const int bb = 16384 + scur * 8192 + (wn * 64 + fr) * 32;
        bf16x8 a[4], b[4];

#pragma unroll
        for (int nb = 0; nb < 4; ++nb)
            b[nb] = *(const bf16x8*)&lds[bb + nb * 512 + ce];
#pragma unroll
        for (int mb = 0; mb < 4; ++mb)
            a[mb] = *(const bf16x8*)&lds[ab + mb * 512 + ce];

        if (u + 1 < NTK) stageA(u + 1);
        if (u + 2 < NTK) stageB(u + 2, snxt);

        __builtin_amdgcn_s_setprio(1);
#pragma unroll
        for (int mb = 0; mb < 4; ++mb)
#pragma unroll
            for (int nb = 0; nb < 4; ++nb)
                acc[mb][nb] = __builtin_amdgcn_mfma_f32_16x16x32_bf16(
                    a[mb], b[nb], acc[mb][nb], 0, 0, 0);
        __builtin_amdgcn_s_setprio(0);

        // counted drain: leave exactly B(u+2) (newest DMA) in flight
        if (u + 2 < NTK) {
            asm volatile("s_waitcnt vmcnt(1)" ::: "memory");
        } else if (u + 1 < NTK) {
            asm volatile("s_waitcnt vmcnt(0)" ::: "memory");
        }
        __builtin_amdgcn_sched_barrier(0);
        __builtin_amdgcn_s_barrier();

        scur = (scur == 2) ? 0 : scur + 1;
        snxt = (snxt == 2) ? 0 : snxt + 1;
    }

    // ---- epilogue: fused bias; C/D layout col=lane&15, row=(lane>>4)*4+reg ----
    const int orow0 = m0 + wm * 64;
    const int ocol0 = n0 + wn * 64;
    float bv[4];
#pragma unroll
    for (int nb = 0; nb < 4; ++nb) {
        const int c = ocol0 + nb * 16 + fr;
        bv[nb] = b_loc[c] + softplus_f(b_std[c]) * eps_b[c];
    }
#pragma unroll
    for (int mb = 0; mb < 4; ++mb)
#pragma unroll
        for (int nb = 0; nb < 4; ++nb)
#pragma unroll
            for (int j = 0; j < 4; ++j)
                C[(size_t)(orow0 + mb * 16 + hi * 4 + j) * N_DIM
                  + ocol0 + nb * 16 + fr] = acc[mb][nb][j] + bv[nb];
}

extern "C" void kernel_launch(void* const* d_in, const int* in_sizes, int n_in,
                              void* d_out, int out_size, void* d_ws, size_t ws_size,
                              hipStream_t stream) {
    const float* x     = (const float*)d_in[0];
    const float* w_loc = (const float*)d_in[1];
    const float* w_std = (const float*)d_in[2];
    const float* b_loc = (const float*)d_in[3];
    const float* b_std = (const float*)d_in[4];
    const float* eps_b = (const float*)d_in[6];
    const float* eps_w = (const float*)d_in[5];
    float* out = (float*)d_out;

    char* ws = (char*)d_ws;
    u16* Xb   = (u16*)ws;                                            // 64 MB
    u16* Wt   = (u16*)(ws + (size_t)M_DIM * K_DIM * 2);              // 32 MB

    (void)hipFuncSetAttribute((const void*)gemm_kernel,
                              hipFuncAttributeMaxDynamicSharedMemorySize, 81920);

    conv_x_kernel<<<2048, 256, 0, stream>>>(x, Xb, (long long)M_DIM * K_DIM / 8);
    wconv_kernel<<<(K_DIM / 64) * (N_DIM / 64), 256, 0, stream>>>(w_loc, w_std, eps_w, Wt);
    gemm_kernel<<<(M_DIM / 256) * (N_DIM / 256), 1024, 81920, stream>>>(
        Xb, Wt, b_loc, b_std, eps_b, out);
}

// Round 13
// 386.859 us; speedup vs baseline: 5.1179x; 1.0726x over previous
//
#include <hip/hip_runtime.h>

typedef unsigned short u16;
typedef unsigned int u32;
typedef __bf16 bf16;
typedef __attribute__((ext_vector_type(8))) bf16 bf16x8;
typedef __attribute__((ext_vector_type(4))) float f32x4;
typedef __attribute__((ext_vector_type(8))) u16 u16x8;
typedef __attribute__((ext_vector_type(4))) u16 u16x4;

#define M_DIM 8192
#define N_DIM 4096
#define K_DIM 4096
#define NTK   (K_DIM / 32)   // 128 K-tiles of 32

__device__ __forceinline__ u16 f2bf(float f) {
    u32 u = __float_as_uint(f);
    u32 r = (u + 0x7fffu + ((u >> 16) & 1u)) >> 16;
    return (u16)r;
}

__device__ __forceinline__ float softplus_f(float x) {
    return fmaxf(x, 0.f) + log1pf(expf(-fabsf(x)));
}

__device__ __forceinline__ void gload_lds16(const void* g, void* l) {
    __builtin_amdgcn_global_load_lds(
        (const __attribute__((address_space(1))) void*)g,
        (__attribute__((address_space(3))) void*)l,
        16, 0, 0);
}

// ---------------- x -> bf16 cast ----------------
__global__ void conv_x_kernel(const float* __restrict__ x, u16* __restrict__ xb,
                              long long n8) {
    long long idx = blockIdx.x * (long long)blockDim.x + threadIdx.x;
    long long stride = gridDim.x * (long long)blockDim.x;
    for (long long i = idx; i < n8; i += stride) {
        const float4* xp = (const float4*)(x + i * 8);
        float4 a = xp[0], b = xp[1];
        u16x8 r;
        r[0] = f2bf(a.x); r[1] = f2bf(a.y); r[2] = f2bf(a.z); r[3] = f2bf(a.w);
        r[4] = f2bf(b.x); r[5] = f2bf(b.y); r[6] = f2bf(b.z); r[7] = f2bf(b.w);
        *(u16x8*)(xb + i * 8) = r;
    }
}

// ------- W sample + transpose (vectorized): Wt[n][k] = bf16(w_loc + sp(w_std)*eps_w) -------
__global__ void wconv_kernel(const float* __restrict__ w_loc,
                             const float* __restrict__ w_std,
                             const float* __restrict__ eps_w,
                             u16* __restrict__ wt) {
    __shared__ u16 t[64][67];
    const int kb = blockIdx.x & 63;
    const int nb = blockIdx.x >> 6;
    const int k0 = kb * 64, n0 = nb * 64;
    const int tr = threadIdx.x >> 4;        // 0..15
    const int tc = (threadIdx.x & 15) * 4;  // 0..60
#pragma unroll
    for (int s = 0; s < 4; ++s) {
        const int kr = s * 16 + tr;
        const size_t off = (size_t)(k0 + kr) * N_DIM + n0 + tc;
        float4 wl = *(const float4*)(w_loc + off);
        float4 ws = *(const float4*)(w_std + off);
        float4 ew = *(const float4*)(eps_w + off);
        t[kr][tc + 0] = f2bf(wl.x + softplus_f(ws.x) * ew.x);
        t[kr][tc + 1] = f2bf(wl.y + softplus_f(ws.y) * ew.y);
        t[kr][tc + 2] = f2bf(wl.z + softplus_f(ws.z) * ew.z);
        t[kr][tc + 3] = f2bf(wl.w + softplus_f(ws.w) * ew.w);
    }
    __syncthreads();
#pragma unroll
    for (int s = 0; s < 4; ++s) {
        const int nr = s * 16 + tr;
        u16x4 v;
        v[0] = t[tc + 0][nr];
        v[1] = t[tc + 1][nr];
        v[2] = t[tc + 2][nr];
        v[3] = t[tc + 3][nr];
        *(u16x4*)&wt[(size_t)(n0 + nr) * K_DIM + k0 + tc] = v;
    }
}

// ------- 128x256 bf16 GEMM, 8 waves, 64 KiB LDS -> 2 INDEPENDENT blocks/CU -------
// C[M][N] = Xb[M][K] @ Wt[N][K]^T + bias(fused). BK=32.
// LDS: A double-buffered [2][128][32] (16K) @0, B TRIPLE-buffered [3][256][32]
// (48K) @8192 elems -> 64 KiB/block. Round-13 lever (r12 root cause): r12's 4
// waves/SIMD were all ONE barrier-locked block -> no independent streams. This
// config co-schedules 2 blocks/CU WITH SLACK (1024 thr <= 2048, 128K LDS <=
// 160K, ~110 VGPR <= 128 cap from __launch_bounds__(512,4)): when one block
// sits at its tile barrier / read phase, the other block's waves keep the
// matrix pipe fed (m114 cross-block overlap) -- the overlap no intra-block
// reorder (r7-r10) could create.
// Per tile u per wave: {b(4)+a(4) ds_reads | stageA(u+1) 1 DMA + stageB(u+2)
// 2 DMAs | 16 MFMA | vmcnt(2) | sched_barrier | s_barrier}. Steady-state
// wait leaves exactly B(u+2) in flight (queue order B(u+1),A(u+1),B(u+2);
// vmcnt(2) retires the first two) -- never drains mid-loop. Slot safety as
// r7: A parity-disjoint; B slots u,u+1,u+2 distinct mod 3; every read is
// consumed by an MFMA before the tile's closing barrier.
// Swizzle (64B rows, r3/r12 measured-0-conflict): read granule
// hi ^ ((fr>>1)&3); DMA source pre-swizzled q=(tid&3)^((tid>>3)&3),
// linear dest (rule #21).
__global__ __launch_bounds__(512, 4) void gemm_kernel(
    const u16* __restrict__ Xb, const u16* __restrict__ Wt,
    const float* __restrict__ b_loc, const float* __restrict__ b_std,
    const float* __restrict__ eps_b, float* __restrict__ C) {
    extern __shared__ __align__(16) u16 lds[];   // 32768 elems = 64 KiB

    const int tid = threadIdx.x;
    const int l  = tid & 63;
    const int w  = tid >> 6;          // wave 0..7
    const int wm = w >> 2;            // 0..1 (64-row band)
    const int wn = w & 3;             // 0..3 (64-col band)

    // T1: XCD-bijective swizzle (1024 blocks, 1024 % 8 == 0)
    const int swz = (blockIdx.x & 7) * 128 + (blockIdx.x >> 3);
    const int m0 = (swz >> 4) * 128;  // 64 M-tiles
    const int n0 = (swz & 15) * 256;  // 16 N-tiles

    const u16* Ab = Xb + (size_t)m0 * K_DIM;
    const u16* Bb = Wt + (size_t)n0 * K_DIM;

    // staging: row = tid>>2, LDS granule tid&3 (linear dest),
    // source granule pre-swizzled: (tid&3) ^ ((row>>1)&3) = (tid&3)^((tid>>3)&3)
    const int sq = ((tid & 3) ^ ((tid >> 3) & 3)) * 8;   // col elems

    // reads: fr = row-within-16, hi = k-granule (0..3)
    const int fr = l & 15, hi = l >> 4;
    const int ce = (hi ^ ((fr >> 1) & 3)) << 3;          // col elems

    auto stageA = [&](int u) {       // 128x32 = 8KB = 512 thr x 16B, 1 DMA
        const u16* g = Ab + (size_t)(tid >> 2) * K_DIM + u * 32 + sq;
        gload_lds16(g, &lds[(u & 1) * 4096 + tid * 8]);
    };
    auto stageB = [&](int u, int slot) {   // 256x32 = 16KB, 2 DMAs
#pragma unroll
        for (int s = 0; s < 2; ++s) {
            const u16* g = Bb + (size_t)(s * 128 + (tid >> 2)) * K_DIM + u * 32 + sq;
            gload_lds16(g, &lds[8192 + slot * 8192 + s * 4096 + tid * 8]);
        }
    };

    f32x4 acc[4][4] = {};

    // ---- prologue: A(0), B(0)->slot0, B(1)->slot1; wait A(0),B(0) ----
    stageA(0);
    stageB(0, 0);
    stageB(1, 1);
    asm volatile("s_waitcnt vmcnt(2)" ::: "memory");
    __builtin_amdgcn_sched_barrier(0);
    __builtin_amdgcn_s_barrier();

    int scur = 0, snxt = 2;   // B slot of tile u; slot for B(u+2)
    for (int u = 0; u < NTK; ++u) {
        const int ab = (u & 1) * 4096 + (wm * 64 + fr) * 32;
        const int bb = 8192 + scur * 8192 + (wn * 64 + fr) * 32;
        bf16x8 a[4], b[4];

#pragma unroll
        for (int nb = 0; nb < 4; ++nb)
            b[nb] = *(const bf16x8*)&lds[bb + nb * 512 + ce];
#pragma unroll
        for (int mb = 0; mb < 4; ++mb)
            a[mb] = *(const bf16x8*)&lds[ab + mb * 512 + ce];

        if (u + 1 < NTK) stageA(u + 1);
        if (u + 2 < NTK) stageB(u + 2, snxt);

        __builtin_amdgcn_s_setprio(1);
#pragma unroll
        for (int mb = 0; mb < 4; ++mb)
#pragma unroll
            for (int nb = 0; nb < 4; ++nb)
                acc[mb][nb] = __builtin_amdgcn_mfma_f32_16x16x32_bf16(
                    a[mb], b[nb], acc[mb][nb], 0, 0, 0);
        __builtin_amdgcn_s_setprio(0);

        // counted drain: retire B(u+1)+A(u+1), leave exactly B(u+2) in flight
        if (u + 2 < NTK) {
            asm volatile("s_waitcnt vmcnt(2)" ::: "memory");
        } else if (u + 1 < NTK) {
            asm volatile("s_waitcnt vmcnt(0)" ::: "memory");
        }
        __builtin_amdgcn_sched_barrier(0);
        __builtin_amdgcn_s_barrier();

        scur = (scur == 2) ? 0 : scur + 1;
        snxt = (snxt == 2) ? 0 : snxt + 1;
    }

    // ---- epilogue: fused bias; C/D layout col=lane&15, row=(lane>>4)*4+reg ----
    const int orow0 = m0 + wm * 64;
    const int ocol0 = n0 + wn * 64;
    float bv[4];
#pragma unroll
    for (int nb = 0; nb < 4; ++nb) {
        const int c = ocol0 + nb * 16 + fr;
        bv[nb] = b_loc[c] + softplus_f(b_std[c]) * eps_b[c];
    }
#pragma unroll
    for (int mb = 0; mb < 4; ++mb)
#pragma unroll
        for (int nb = 0; nb < 4; ++nb)
#pragma unroll
            for (int j = 0; j < 4; ++j)
                C[(size_t)(orow0 + mb * 16 + hi * 4 + j) * N_DIM
                  + ocol0 + nb * 16 + fr] = acc[mb][nb][j] + bv[nb];
}

extern "C" void kernel_launch(void* const* d_in, const int* in_sizes, int n_in,
                              void* d_out, int out_size, void* d_ws, size_t ws_size,
                              hipStream_t stream) {
    const float* x     = (const float*)d_in[0];
    const float* w_loc = (const float*)d_in[1];
    const float* w_std = (const float*)d_in[2];
    const float* b_loc = (const float*)d_in[3];
    const float* b_std = (const float*)d_in[4];
    const float* eps_w = (const float*)d_in[5];
    const float* eps_b = (const float*)d_in[6];
    float* out = (float*)d_out;

    char* ws = (char*)d_ws;
    u16* Xb   = (u16*)ws;                                            // 64 MB
    u16* Wt   = (u16*)(ws + (size_t)M_DIM * K_DIM * 2);              // 32 MB

    (void)hipFuncSetAttribute((const void*)gemm_kernel,
                              hipFuncAttributeMaxDynamicSharedMemorySize, 65536);

    conv_x_kernel<<<2048, 256, 0, stream>>>(x, Xb, (long long)M_DIM * K_DIM / 8);
    wconv_kernel<<<(K_DIM / 64) * (N_DIM / 64), 256, 0, stream>>>(w_loc, w_std, eps_w, Wt);
    gemm_kernel<<<(M_DIM / 128) * (N_DIM / 256), 512, 65536, stream>>>(
        Xb, Wt, b_loc, b_std, eps_b, out);
}

// Round 14
// 330.786 us; speedup vs baseline: 5.9855x; 1.1695x over previous
//
#include <hip/hip_runtime.h>

typedef unsigned short u16;
typedef unsigned int u32;
typedef __bf16 bf16;
typedef __attribute__((ext_vector_type(8))) bf16 bf16x8;
typedef __attribute__((ext_vector_type(4))) float f32x4;
typedef __attribute__((ext_vector_type(8))) u16 u16x8;
typedef __attribute__((ext_vector_type(4))) u16 u16x4;

#define M_DIM 8192
#define N_DIM 4096
#define K_DIM 4096
#define NTK   (K_DIM / 64)   // 64 K-tiles of 64

__device__ __forceinline__ u16 f2bf(float f) {
    u32 u = __float_as_uint(f);
    u32 r = (u + 0x7fffu + ((u >> 16) & 1u)) >> 16;
    return (u16)r;
}

__device__ __forceinline__ float softplus_f(float x) {
    return fmaxf(x, 0.f) + log1pf(expf(-fabsf(x)));
}

__device__ __forceinline__ void gload_lds16(const void* g, void* l) {
    __builtin_amdgcn_global_load_lds(
        (const __attribute__((address_space(1))) void*)g,
        (__attribute__((address_space(3))) void*)l,
        16, 0, 0);
}

// ---- fused prep: blocks [0,2048) cast x->bf16; blocks [2048,6144) W-sample+transpose ----
// The two halves touch disjoint data (x->Xb vs w_*->Wt); block-level split, no
// divergence within a block. Their memory streams share the HBM pipe in ONE
// dispatch (sequential floors 20+36us -> concurrent ~max+delta) and one kernel
// boundary is removed.
__global__ void prep_kernel(const float* __restrict__ x, u16* __restrict__ xb,
                            const float* __restrict__ w_loc,
                            const float* __restrict__ w_std,
                            const float* __restrict__ eps_w,
                            u16* __restrict__ wt) {
    __shared__ u16 t[64][67];
    if (blockIdx.x < 2048) {
        // ---- conv_x: 8192x4096 bf16 cast, float4-pair loads, u16x8 stores ----
        const long long n8 = (long long)M_DIM * K_DIM / 8;
        long long idx = blockIdx.x * (long long)blockDim.x + threadIdx.x;
        const long long stride = 2048LL * blockDim.x;
        for (long long i = idx; i < n8; i += stride) {
            const float4* xp = (const float4*)(x + i * 8);
            float4 a = xp[0], b = xp[1];
            u16x8 r;
            r[0] = f2bf(a.x); r[1] = f2bf(a.y); r[2] = f2bf(a.z); r[3] = f2bf(a.w);
            r[4] = f2bf(b.x); r[5] = f2bf(b.y); r[6] = f2bf(b.z); r[7] = f2bf(b.w);
            *(u16x8*)(xb + i * 8) = r;
        }
    } else {
        // ---- wconv: Wt[n][k] = bf16(w_loc + softplus(w_std)*eps_w), 64x64 tiles ----
        const int bid = blockIdx.x - 2048;
        const int kb = bid & 63;
        const int nb = bid >> 6;
        const int k0 = kb * 64, n0 = nb * 64;
        const int tr = threadIdx.x >> 4;        // 0..15
        const int tc = (threadIdx.x & 15) * 4;  // 0..60
#pragma unroll
        for (int s = 0; s < 4; ++s) {
            const int kr = s * 16 + tr;
            const size_t off = (size_t)(k0 + kr) * N_DIM + n0 + tc;
            float4 wl = *(const float4*)(w_loc + off);
            float4 ws = *(const float4*)(w_std + off);
            float4 ew = *(const float4*)(eps_w + off);
            t[kr][tc + 0] = f2bf(wl.x + softplus_f(ws.x) * ew.x);
            t[kr][tc + 1] = f2bf(wl.y + softplus_f(ws.y) * ew.y);
            t[kr][tc + 2] = f2bf(wl.z + softplus_f(ws.z) * ew.z);
            t[kr][tc + 3] = f2bf(wl.w + softplus_f(ws.w) * ew.w);
        }
        __syncthreads();
#pragma unroll
        for (int s = 0; s < 4; ++s) {
            const int nr = s * 16 + tr;
            u16x4 v;
            v[0] = t[tc + 0][nr];
            v[1] = t[tc + 1][nr];
            v[2] = t[tc + 2][nr];
            v[3] = t[tc + 3][nr];
            *(u16x4*)&wt[(size_t)(n0 + nr) * K_DIM + k0 + tc] = v;
        }
    }
}

// ------- 256x256 bf16 GEMM, 1 barrier/tile, 4 quadrant-clusters/tile (r10 best) -------
// C[M][N] = Xb[M][K] @ Wt[N][K]^T + bias(fused). BK=64, 8 waves (2Mx4N), 160 KiB
// LDS: A double-buffered [2][256][64] @0, B TRIPLE-buffered [3][256][64] @32768.
// 64 MFMA/tile in 4 quadrant clusters of 16 (Q0 ks0 m0-3, Q1 ks0 m4-7, Q2 ks1
// m0-3, Q3 ks1 m4-7), each cluster's ds_reads immediately before it, NO forced
// lgkm/barrier between clusters (compiler emits fine-grained lgkmcnt; while a
// cluster's MFMAs drain, the wave issues the next cluster's reads). Same-acc
// clusters are 32 MFMAs apart. Race discipline (proven r7): every ds_read is
// consumed before the tile's closing sched_barrier(0)+s_barrier; stage targets
// >=1 tile from any live reader (A parity, B slots u,u+1,u+2 distinct mod 3);
// tile-end vmcnt(4) leaves exactly B(u+2) in flight -- never drains mid-loop.
// Staging/read addresses byte-identical to r7/r10 (measured 0 conflicts).
__global__ __launch_bounds__(512, 2) void gemm_kernel(
    const u16* __restrict__ Xb, const u16* __restrict__ Wt,
    const float* __restrict__ b_loc, const float* __restrict__ b_std,
    const float* __restrict__ eps_b, float* __restrict__ C) {
    extern __shared__ __align__(16) u16 lds[];   // 81920 elems = 160 KiB

    const int tid = threadIdx.x;
    const int l  = tid & 63;
    const int w  = tid >> 6;          // wave 0..7
    const int wm = w >> 2;            // 0..1
    const int wn = w & 3;             // 0..3

    // T1: XCD-bijective swizzle (512 blocks, 512 % 8 == 0)
    const int swz = (blockIdx.x & 7) * 64 + (blockIdx.x >> 3);
    const int m0 = (swz >> 4) * 256;  // 32 M-tiles
    const int n0 = (swz & 15) * 256;  // 16 N-tiles

    const u16* Ab = Xb + (size_t)m0 * K_DIM;
    const u16* Bb = Wt + (size_t)n0 * K_DIM;

    const int srow = tid >> 3;
    const int sq   = ((tid & 7) ^ (srow & 7)) * 8;    // pre-swizzled col elems

    const int fr = l & 15, hi = l >> 4;
    const int g0 = (hi ^ (fr & 7)) << 3;              // ks0 col elems; ks1: ^32

    auto stageA = [&](int u, int h) {
#pragma unroll
        for (int s = 0; s < 2; ++s) {
            const u16* g = Ab + (size_t)(h * 128 + s * 64 + srow) * K_DIM + u * 64 + sq;
            gload_lds16(g, &lds[(u & 1) * 16384 + h * 8192 + s * 4096 + tid * 8]);
        }
    };
    auto stageB = [&](int u, int slot, int h) {
#pragma unroll
        for (int s = 0; s < 2; ++s) {
            const u16* g = Bb + (size_t)(h * 128 + s * 64 + srow) * K_DIM + u * 64 + sq;
            gload_lds16(g, &lds[32768 + slot * 16384 + h * 8192 + s * 4096 + tid * 8]);
        }
    };

    f32x4 acc[8][4] = {};

    // ---- prologue: A(0), B(0)->slot0, B(1)->slot1; wait A(0),B(0) ----
    stageA(0, 0); stageA(0, 1);
    stageB(0, 0, 0); stageB(0, 0, 1);
    stageB(1, 1, 0); stageB(1, 1, 1);
    asm volatile("s_waitcnt vmcnt(4)" ::: "memory");
    __builtin_amdgcn_sched_barrier(0);
    __builtin_amdgcn_s_barrier();

#define MFMA16(O, AV, BV)                                                     \
    _Pragma("unroll") for (int mb = 0; mb < 4; ++mb)                          \
    _Pragma("unroll") for (int nb = 0; nb < 4; ++nb)                          \
        acc[(O) + mb][nb] = __builtin_amdgcn_mfma_f32_16x16x32_bf16(          \
            AV[mb], BV[nb], acc[(O) + mb][nb], 0, 0, 0);

    int scur = 0, snxt = 2;   // B slot of tile u; slot for B(u+2)
    for (int u = 0; u < NTK; ++u) {
        const int ab = (u & 1) * 16384 + (wm * 128 + fr) * 64;
        const int bb = 32768 + scur * 16384 + (wn * 64 + fr) * 64;
        bf16x8 b0[4], b1[4], aA[4], aB[4], aC[4], aD[4];

        // ---- Q0: b-ks0(4) + a-ks0 m0-3(4) reads; stage A(u+1); 16 MFMA ----
#pragma unroll
        for (int nb = 0; nb < 4; ++nb)
            b0[nb] = *(const bf16x8*)&lds[bb + nb * 1024 + g0];
#pragma unroll
        for (int mb = 0; mb < 4; ++mb)
            aA[mb] = *(const bf16x8*)&lds[ab + mb * 1024 + g0];
        if (u + 1 < NTK) { stageA(u + 1, 0); stageA(u + 1, 1); }
        __builtin_amdgcn_s_setprio(1);
        MFMA16(0, aA, b0);
        __builtin_amdgcn_s_setprio(0);

        // ---- Q1: a-ks0 m4-7(4) reads; 16 MFMA ----
#pragma unroll
        for (int mb = 0; mb < 4; ++mb)
            aB[mb] = *(const bf16x8*)&lds[ab + (mb + 4) * 1024 + g0];
        __builtin_amdgcn_s_setprio(1);
        MFMA16(4, aB, b0);
        __builtin_amdgcn_s_setprio(0);

        // ---- Q2: b-ks1(4) + a-ks1 m0-3(4) reads; stage B(u+2); 16 MFMA ----
#pragma unroll
        for (int nb = 0; nb < 4; ++nb)
            b1[nb] = *(const bf16x8*)&lds[bb + nb * 1024 + (g0 ^ 32)];
#pragma unroll
        for (int mb = 0; mb < 4; ++mb)
            aC[mb] = *(const bf16x8*)&lds[ab + mb * 1024 + (g0 ^ 32)];
        if (u + 2 < NTK) { stageB(u + 2, snxt, 0); stageB(u + 2, snxt, 1); }
        __builtin_amdgcn_s_setprio(1);
        MFMA16(0, aC, b1);
        __builtin_amdgcn_s_setprio(0);

        // ---- Q3: a-ks1 m4-7(4) reads; 16 MFMA ----
#pragma unroll
        for (int mb = 0; mb < 4; ++mb)
            aD[mb] = *(const bf16x8*)&lds[ab + (mb + 4) * 1024 + (g0 ^ 32)];
        __builtin_amdgcn_s_setprio(1);
        MFMA16(4, aD, b1);
        __builtin_amdgcn_s_setprio(0);

        // counted drain: leave exactly B(u+2) (newest 4 DMAs) in flight
        if (u + 2 < NTK) {
            asm volatile("s_waitcnt vmcnt(4)" ::: "memory");
        } else if (u + 1 < NTK) {
            asm volatile("s_waitcnt vmcnt(0)" ::: "memory");
        }
        __builtin_amdgcn_sched_barrier(0);
        __builtin_amdgcn_s_barrier();

        scur = (scur == 2) ? 0 : scur + 1;
        snxt = (snxt == 2) ? 0 : snxt + 1;
    }
#undef MFMA16

    // ---- epilogue: fused bias; C/D layout col=lane&15, row=(lane>>4)*4+reg ----
    const int orow0 = m0 + wm * 128;
    const int ocol0 = n0 + wn * 64;
    float bv[4];
#pragma unroll
    for (int nb = 0; nb < 4; ++nb) {
        const int c = ocol0 + nb * 16 + fr;
        bv[nb] = b_loc[c] + softplus_f(b_std[c]) * eps_b[c];
    }
#pragma unroll
    for (int mb = 0; mb < 8; ++mb)
#pragma unroll
        for (int nb = 0; nb < 4; ++nb)
#pragma unroll
            for (int j = 0; j < 4; ++j)
                C[(size_t)(orow0 + mb * 16 + hi * 4 + j) * N_DIM
                  + ocol0 + nb * 16 + fr] = acc[mb][nb][j] + bv[nb];
}

extern "C" void kernel_launch(void* const* d_in, const int* in_sizes, int n_in,
                              void* d_out, int out_size, void* d_ws, size_t ws_size,
                              hipStream_t stream) {
    const float* x     = (const float*)d_in[0];
    const float* w_loc = (const float*)d_in[1];
    const float* w_std = (const float*)d_in[2];
    const float* b_loc = (const float*)d_in[3];
    const float* b_std = (const float*)d_in[4];
    const float* eps_w = (const float*)d_in[5];
    const float* eps_b = (const float*)d_in[6];
    float* out = (float*)d_out;

    char* ws = (char*)d_ws;
    u16* Xb   = (u16*)ws;                                            // 64 MB
    u16* Wt   = (u16*)(ws + (size_t)M_DIM * K_DIM * 2);              // 32 MB

    (void)hipFuncSetAttribute((const void*)gemm_kernel,
                              hipFuncAttributeMaxDynamicSharedMemorySize, 163840);

    prep_kernel<<<2048 + (K_DIM / 64) * (N_DIM / 64), 256, 0, stream>>>(
        x, Xb, w_loc, w_std, eps_w, Wt);
    gemm_kernel<<<(M_DIM / 256) * (N_DIM / 256), 512, 163840, stream>>>(
        Xb, Wt, b_loc, b_std, eps_b, out);
}